// Round 7
// baseline (1553.817 us; speedup 1.0000x reference)
//
#include <hip/hip_runtime.h>
#include <math.h>

// RNNLayer: out[t] = tanh(x[t] @ Wx + b + h_{t-1} @ Wh), h_{-1} = h0
// S=128, B=128, D=1024. Inputs/outputs fp32.
//
// Round 12: ONE kernel. The separate xp phase (271 us, serial before the
// scan) is deleted; xp compute is fused into the scan's 93%-idle step.
//   - Each block holds BOTH Wh and Wx 64-col slices register-resident as
//     bf16 hi/lo k-half fragments (256 VGPRs of weights, ~310 total; NO
//     launch_bounds min-waves arg -> no forced cap -> no round-4 spill).
//   - x[t] is an input (zero deps): staged one step ahead via the verified
//     xp_pers T14 pattern (global->regs before B1, convert+LDS after B2).
//     LDS: hS 33K + xHi 33K + xLo 33K + redS 4K = 103 KB, 1 block/CU.
//   - MFMA: 5 per s-iter (h*Whhi, h*Whlo, xh*Wxhi, xl*Wxhi, xh*Wxlo) into
//     ONE accumulator; + bias before tanh. Same products as rounds 3-11,
//     summed in one fp32 chain -> absmax unchanged.
//   - The scan's out[]-readback of xp (xpv nt-loads, ~61 MB FETCH) is gone;
//     out[] is now write-only.
// Exchange/tail protocol: round-5 scan VERBATIM (verified 477 us; round-6's
// per-wave RMW counter post regressed 123 us and is reverted):
//   bf16 hX side-channel (parity double-buffered), per-group 16-block flags,
//   drain-all -> barrier -> tid0 single flag store -> out nt-stores ->
//   tid<16 spin -> barrier.
// Workspace: flags 8 KB @0, hX 512 KB @8192.

#define DIM 1024
#define BATCH 128
#define SEQ 128
#define BD (BATCH * DIM)
#define NBLK 128
#define GRP 16        // blocks per batch-group
#define HSTR 1032     // LDS row stride in ushorts (bank spread)
#define FLAGSTR 16    // uints per flag slot (64 B)
#define HXGRP 16384   // ushorts per hX group slab (16 rows x 1024 cols)

typedef __attribute__((ext_vector_type(8))) short bf16x8;
typedef __attribute__((ext_vector_type(4))) float f32x4;

static __device__ __forceinline__ unsigned short f2bf_rne(float f) {
    unsigned u = __builtin_bit_cast(unsigned, f);
    unsigned r = (u + 0x7FFFu + ((u >> 16) & 1u)) >> 16;
    return (unsigned short)r;
}
static __device__ __forceinline__ float bf2f(unsigned short h) {
    return __builtin_bit_cast(float, ((unsigned)h) << 16);
}

// fp32 pair -> bf16 hi (truncation) + lo (rne of residual); hi+lo ~ f to 2^-17
static __device__ __forceinline__ void split_pair(
    unsigned long long v, unsigned& hp, unsigned& lp)
{
    const unsigned u0 = (unsigned)v;
    const unsigned u1 = (unsigned)(v >> 32);
    const float f0 = __builtin_bit_cast(float, u0);
    const float f1 = __builtin_bit_cast(float, u1);
    hp = (u0 >> 16) | (u1 & 0xFFFF0000u);
    const float r0 = f0 - __builtin_bit_cast(float, u0 & 0xFFFF0000u);
    const float r1 = f1 - __builtin_bit_cast(float, u1 & 0xFFFF0000u);
    lp = (unsigned)f2bf_rne(r0) | ((unsigned)f2bf_rne(r1) << 16);
}

// ---------------------------------------------------------------------------
// Fused persistent scan. Block: bt = bid&7 (XCD-affine group), ct = bid>>3.
// Wave w (of 8): col-tile (w>>1), k-half (w&1). Wh AND Wx bf16 hi/lo resident.
// ---------------------------------------------------------------------------
__global__ __launch_bounds__(512) void rnn_fused(
    const float* __restrict__ x,
    const float* __restrict__ h0,
    const float* __restrict__ Wx,
    const float* __restrict__ Wh,
    const float* __restrict__ bias,
    float* out,
    unsigned* flags,
    unsigned short* hX)
{
    __shared__ unsigned short hS [16 * HSTR];   // 33 KB bf16 h tile
    __shared__ unsigned short xHi[16 * HSTR];   // 33 KB x tile hi
    __shared__ unsigned short xLo[16 * HSTR];   // 33 KB x tile lo
    __shared__ f32x4 redS[256];                 // 4 KB k-half exchange

    const int tid = threadIdx.x;
    const int p   = blockIdx.x;
    const int bt  = p & 7;           // XCD-affine: group bt lives on one XCD
    const int ct  = p >> 3;
    const int lbid = bt * 16 + ct;   // logical id for flag slots
    const int B0  = bt * 16;
    const int Cb  = ct * 64;

    const int w = tid >> 6;
    const int l = tid & 63;
    const int n = l & 15;
    const int q = l >> 4;
    const int cb = Cb + (w >> 1) * 16;
    const int K0 = (w & 1) * 512;

    // ---- resident Wh + Wx fragments (bf16 hi + lo), k-half split ----
    bf16x8 Bhi[16], Blo[16], Xhi[16], Xlo[16];
    #pragma unroll
    for (int s = 0; s < 16; ++s) {
        bf16x8 hi, lo, xh, xl;
        #pragma unroll
        for (int j = 0; j < 8; ++j) {
            const int k = K0 + 32 * s + q * 8 + j;
            const float wv = Wh[(size_t)k * DIM + cb + n];
            const unsigned short h16 = f2bf_rne(wv);
            hi[j] = (short)h16;
            lo[j] = (short)f2bf_rne(wv - bf2f(h16));
            const float xv = Wx[(size_t)k * DIM + cb + n];
            const unsigned short x16 = f2bf_rne(xv);
            xh[j] = (short)x16;
            xl[j] = (short)f2bf_rne(xv - bf2f(x16));
        }
        Bhi[s] = hi;  Blo[s] = lo;
        Xhi[s] = xh;  Xlo[s] = xl;
    }
    const float bv = bias[cb + n];

    const int sr = tid >> 5;           // x / h0 staging: row (32 threads/row)
    const int su = tid & 31;           // x / h0 staging: ulong lane in row
    const int qq = tid & 3;            // hX staging: row quad
    const int c0 = (tid >> 2) & 127;   // hX staging: col-group base

    // ---- prologue: stage x[0] tile fully (load + convert + LDS) ----
    {
        const float* xT = x + (size_t)B0 * DIM;   // t = 0
        const unsigned long long* srow =
            (const unsigned long long*)(xT + (size_t)sr * DIM);
        unsigned short* dh = &xHi[sr * HSTR];
        unsigned short* dl = &xLo[sr * HSTR];
        #pragma unroll
        for (int i = 0; i < 16; ++i) {
            unsigned hp, lp;
            split_pair(srow[su + 32 * i], hp, lp);
            *(unsigned*)(dh + 2 * (su + 32 * i)) = hp;
            *(unsigned*)(dl + 2 * (su + 32 * i)) = lp;
        }
    }

    for (int t = 0; t < SEQ; ++t) {
        float* outT = out + (size_t)t * BD;

        // ---- issue NEXT step's x loads (no deps; latency hides under step)
        unsigned long long xr[16];
        if (t + 1 < SEQ) {
            const float* xN = x + (size_t)(t + 1) * BD + (size_t)B0 * DIM;
            const unsigned long long* srow =
                (const unsigned long long*)(xN + (size_t)sr * DIM);
            #pragma unroll
            for (int i = 0; i < 16; ++i) xr[i] = srow[su + 32 * i];
        }

        // ---- stage h tile into row-major LDS ----
        if (t == 0) {
            const float* hsrc = h0 + (size_t)B0 * DIM;
            const unsigned long long* srow =
                (const unsigned long long*)(hsrc + (size_t)sr * DIM);
            unsigned short* drow = &hS[sr * HSTR];
            #pragma unroll
            for (int i = 0; i < 16; ++i) {
                const unsigned long long v = srow[su + 32 * i];
                const float f0 = __builtin_bit_cast(float, (unsigned)(v & 0xFFFFFFFFull));
                const float f1 = __builtin_bit_cast(float, (unsigned)(v >> 32));
                const unsigned pk =
                    (unsigned)f2bf_rne(f0) | ((unsigned)f2bf_rne(f1) << 16);
                *(unsigned*)(drow + 2 * (su + 32 * i)) = pk;
            }
        } else {
            // bf16 side-channel: 8 x 8B bypass loads + in-register transpose
            const unsigned short* gX = hX + (size_t)((t - 1) & 1) * (8 * HXGRP)
                                          + (size_t)bt * HXGRP;
            #pragma unroll
            for (int half = 0; half < 2; ++half) {
                const int cp = c0 + half * 128;
                unsigned long long L[4];
                #pragma unroll
                for (int cc = 0; cc < 4; ++cc)
                    L[cc] = __hip_atomic_load(
                        (const unsigned long long*)(gX + (size_t)(4 * cp + cc) * 16 + qq * 4),
                        __ATOMIC_RELAXED, __HIP_MEMORY_SCOPE_AGENT);
                #pragma unroll
                for (int i = 0; i < 2; ++i) {
                    const unsigned a0 = (unsigned)(L[0] >> (32 * i));
                    const unsigned a1 = (unsigned)(L[1] >> (32 * i));
                    const unsigned a2 = (unsigned)(L[2] >> (32 * i));
                    const unsigned a3 = (unsigned)(L[3] >> (32 * i));
                    const unsigned r0w0 = (a0 & 0xFFFFu) | (a1 << 16);
                    const unsigned r0w1 = (a2 & 0xFFFFu) | (a3 << 16);
                    const unsigned r1w0 = (a0 >> 16) | (a1 & 0xFFFF0000u);
                    const unsigned r1w1 = (a2 >> 16) | (a3 & 0xFFFF0000u);
                    *(unsigned long long*)&hS[(4 * qq + 2 * i) * HSTR + 4 * cp] =
                        (unsigned long long)r0w0 | ((unsigned long long)r0w1 << 32);
                    *(unsigned long long*)&hS[(4 * qq + 2 * i + 1) * HSTR + 4 * cp] =
                        (unsigned long long)r1w0 | ((unsigned long long)r1w1 << 32);
                }
            }
        }

        __syncthreads();   // B1: hS(t) ready; xHi/xLo(t) ready (written last iter)

        // ---- MFMA over this wave's k-half: h@Wh (hi+lo) + x@Wx (hh+lh+hl)
        f32x4 acc = {0.f, 0.f, 0.f, 0.f};
        {
            const unsigned short* hrow = &hS [(l & 15) * HSTR + K0];
            const unsigned short* xrh  = &xHi[(l & 15) * HSTR + K0];
            const unsigned short* xrl  = &xLo[(l & 15) * HSTR + K0];
            #pragma unroll
            for (int s = 0; s < 16; ++s) {
                const bf16x8 a  = *(const bf16x8*)(hrow + 32 * s + 8 * q);
                const bf16x8 xh = *(const bf16x8*)(xrh  + 32 * s + 8 * q);
                const bf16x8 xl = *(const bf16x8*)(xrl  + 32 * s + 8 * q);
                acc = __builtin_amdgcn_mfma_f32_16x16x32_bf16(a,  Bhi[s], acc, 0, 0, 0);
                acc = __builtin_amdgcn_mfma_f32_16x16x32_bf16(a,  Blo[s], acc, 0, 0, 0);
                acc = __builtin_amdgcn_mfma_f32_16x16x32_bf16(xh, Xhi[s], acc, 0, 0, 0);
                acc = __builtin_amdgcn_mfma_f32_16x16x32_bf16(xl, Xhi[s], acc, 0, 0, 0);
                acc = __builtin_amdgcn_mfma_f32_16x16x32_bf16(xh, Xlo[s], acc, 0, 0, 0);
            }
        }

        if (w & 1) redS[(w >> 1) * 64 + l] = acc;
        __syncthreads();   // B2: all LDS reads of hS/xHi/xLo(t) done

        float v0, v1, v2, v3;
        if (!(w & 1)) {
            const f32x4 pp = redS[(w >> 1) * 64 + l];
            // C/D layout: col = lane&15, row = q*4 + reg
            v0 = tanhf(acc[0] + pp[0] + bv);
            v1 = tanhf(acc[1] + pp[1] + bv);
            v2 = tanhf(acc[2] + pp[2] + bv);
            v3 = tanhf(acc[3] + pp[3] + bv);
            // bf16 side-channel store (the only store gating the flag)
            const unsigned p0 = (unsigned)f2bf_rne(v0) | ((unsigned)f2bf_rne(v1) << 16);
            const unsigned p1 = (unsigned)f2bf_rne(v2) | ((unsigned)f2bf_rne(v3) << 16);
            unsigned short* gW = hX + (size_t)(t & 1) * (8 * HXGRP) + (size_t)bt * HXGRP;
            __hip_atomic_store(
                (unsigned long long*)(gW + (size_t)(cb + n) * 16 + q * 4),
                (unsigned long long)p0 | ((unsigned long long)p1 << 32),
                __ATOMIC_RELAXED, __HIP_MEMORY_SCOPE_AGENT);
        }

        if (t < SEQ - 1) {
            // drain stores to the coherence point, then post my flag
            asm volatile("s_waitcnt vmcnt(0)" ::: "memory");
            __syncthreads();   // B3
            if (tid == 0)
                __hip_atomic_store(&flags[lbid * FLAGSTR], (unsigned)(t + 1),
                                   __ATOMIC_RELAXED, __HIP_MEMORY_SCOPE_AGENT);
        }

        // fp32 output stores AFTER the flag post: complete under the spin
        if (!(w & 1)) {
            __builtin_nontemporal_store(v0, &outT[(size_t)(B0 + q * 4 + 0) * DIM + cb + n]);
            __builtin_nontemporal_store(v1, &outT[(size_t)(B0 + q * 4 + 1) * DIM + cb + n]);
            __builtin_nontemporal_store(v2, &outT[(size_t)(B0 + q * 4 + 2) * DIM + cb + n]);
            __builtin_nontemporal_store(v3, &outT[(size_t)(B0 + q * 4 + 3) * DIM + cb + n]);
        }

        // ---- convert + write NEXT step's x tile (xHi/xLo free after B2) ----
        if (t + 1 < SEQ) {
            unsigned short* dh = &xHi[sr * HSTR];
            unsigned short* dl = &xLo[sr * HSTR];
            #pragma unroll
            for (int i = 0; i < 16; ++i) {
                unsigned hp, lp;
                split_pair(xr[i], hp, lp);
                *(unsigned*)(dh + 2 * (su + 32 * i)) = hp;
                *(unsigned*)(dl + 2 * (su + 32 * i)) = lp;
            }
        }

        if (t < SEQ - 1) {
            // threads 0..15 each watch one block of this bt-group
            if (tid < GRP) {
                const unsigned* slot = &flags[(bt * GRP + tid) * FLAGSTR];
                while (__hip_atomic_load(slot, __ATOMIC_RELAXED,
                                         __HIP_MEMORY_SCOPE_AGENT) < (unsigned)(t + 1))
                    __builtin_amdgcn_s_sleep(1);
            }
            __syncthreads();   // B4: whole group advanced; safe to reuse slabs
        }
    }
}

// ---------------------------------------------------------------------------
extern "C" void kernel_launch(void* const* d_in, const int* in_sizes, int n_in,
                              void* d_out, int out_size, void* d_ws, size_t ws_size,
                              hipStream_t stream) {
    const float* x  = (const float*)d_in[0];   // [S,B,D]
    const float* h0 = (const float*)d_in[1];   // [B,D]
    const float* Wx = (const float*)d_in[2];   // [D,D]
    const float* Wh = (const float*)d_in[3];   // [D,D]
    const float* b  = (const float*)d_in[4];   // [D]
    float* out = (float*)d_out;                // [S,B,D]
    unsigned* flags = (unsigned*)d_ws;                            // 8 KB
    unsigned short* hX = (unsigned short*)((char*)d_ws + 8192);   // 512 KB

    hipMemsetAsync(d_ws, 0, NBLK * FLAGSTR * sizeof(unsigned), stream);

    rnn_fused<<<dim3(NBLK), dim3(512), 0, stream>>>(
        x, h0, Wx, Wh, b, out, flags, hX);
}

// Round 8
// 772.282 us; speedup vs baseline: 2.0120x; 2.0120x over previous
//
#include <hip/hip_runtime.h>
#include <math.h>

// RNNLayer: out[t] = tanh(x[t] @ Wx + b + h_{t-1} @ Wh), h_{-1} = h0
// S=128, B=128, D=1024. Inputs/outputs fp32.
//
// Round 13: two kernels (round-7 full fusion is structurally impossible:
// Wh+Wx hi/lo weights = 512 KB/block = the whole VGPR file -> spill).
//
// Phase 1: xp_pers VERBATIM from round 6 (verified 271 us).
// Phase 2: rnn_scan with PER-WAVE TAGGED MAILBOXES (no flags, no tail
//   barriers). Replaces round-5's drain-all -> B3 -> tid0 flag -> 16-flag
//   spin -> B4 chain (and round-6's regressed RMW counters):
//   - producer even-wave: 64 x 8B hX unit stores -> s_waitcnt vmcnt(0)
//     (wave-scoped: drains only this wave) -> lane 0 posts tag = t+1 for its
//     (group bt, global col-tile) slot. 4 tags/block, 64 tags/group.
//   - consumer thread: polls the 2 tags covering its 8 units (col-tiles
//     c0>>2 and 32+(c0>>2)), compiler barrier, then 8 x 8B bypass loads.
//   - Parity-slab safety WITHOUT the group barrier: a block writes slab
//     (t+1)&1 only after observing all tags >= t+1; tag t+1 is posted only
//     after that block's step-t staging reads of slab (t-1)&1 completed ->
//     the tag value itself carries the anti-dependency. Max observable tag
//     during step-t staging is t+1, so ">= t" polls are exact.
// Workspace: tags 32 KB @0 (memset once), hX 512 KB @32768.

#define DIM 1024
#define BATCH 128
#define SEQ 128
#define BD (BATCH * DIM)
#define NBLK 128
#define HSTR 1032     // LDS row stride in ushorts (bank spread)
#define FLAGSTR 16    // uints per tag slot (64 B)
#define XNB 256       // xp blocks
#define HXGRP 16384   // ushorts per hX group slab (16 rows x 1024 cols)

typedef __attribute__((ext_vector_type(8))) short bf16x8;
typedef __attribute__((ext_vector_type(4))) float f32x4;

static __device__ __forceinline__ unsigned short f2bf_rne(float f) {
    unsigned u = __builtin_bit_cast(unsigned, f);
    unsigned r = (u + 0x7FFFu + ((u >> 16) & 1u)) >> 16;
    return (unsigned short)r;
}
static __device__ __forceinline__ float bf2f(unsigned short h) {
    return __builtin_bit_cast(float, ((unsigned)h) << 16);
}

// fp32 pair -> bf16 hi (truncation) + lo (rne of residual); hi+lo ~ f to 2^-17
static __device__ __forceinline__ void split_pair(
    unsigned long long v, unsigned& hp, unsigned& lp)
{
    const unsigned u0 = (unsigned)v;
    const unsigned u1 = (unsigned)(v >> 32);
    const float f0 = __builtin_bit_cast(float, u0);
    const float f1 = __builtin_bit_cast(float, u1);
    hp = (u0 >> 16) | (u1 & 0xFFFF0000u);
    const float r0 = f0 - __builtin_bit_cast(float, u0 & 0xFFFF0000u);
    const float r1 = f1 - __builtin_bit_cast(float, u1 & 0xFFFF0000u);
    lp = (unsigned)f2bf_rne(r0) | ((unsigned)f2bf_rne(r1) << 16);
}

// ---------------------------------------------------------------------------
// Phase 1: persistent xp GEMM (round-6 verbatim, verified 271 us).
// ---------------------------------------------------------------------------
__global__ __launch_bounds__(512) void xp_pers(
    const float* __restrict__ x,
    const float* __restrict__ Wx,
    const float* __restrict__ bias,
    float* __restrict__ out)
{
    __shared__ unsigned short hHi[16 * HSTR];
    __shared__ unsigned short hLo[16 * HSTR];
    __shared__ f32x4 redS[256];

    const int tid = threadIdx.x;
    const int bid = blockIdx.x;
    const int g   = bid & 15;        // (tg,bt)
    const int ct  = bid >> 4;        // 0..15
    const int tg  = g >> 3;
    const int bt  = g & 7;
    const int B0  = bt * 16;
    const int Cb  = ct * 64;
    const int NT  = SEQ / 2;

    const int w = tid >> 6;
    const int l = tid & 63;
    const int n = l & 15;
    const int q = l >> 4;
    const int cb = Cb + (w >> 1) * 16;
    const int K0 = (w & 1) * 512;

    bf16x8 Bhi[16], Blo[16];
    #pragma unroll
    for (int s = 0; s < 16; ++s) {
        bf16x8 hi, lo;
        #pragma unroll
        for (int j = 0; j < 8; ++j) {
            const int k = K0 + 32 * s + q * 8 + j;
            const float wv = Wx[(size_t)k * DIM + cb + n];
            const unsigned short h16 = f2bf_rne(wv);
            hi[j] = (short)h16;
            lo[j] = (short)f2bf_rne(wv - bf2f(h16));
        }
        Bhi[s] = hi;
        Blo[s] = lo;
    }
    const float bv = bias[cb + n];

    const int sr = tid >> 5;    // staging: row 0..15 (32 threads per row)
    const int su = tid & 31;    // staging: ulong lane within row

    {
        const float* xT = x + (size_t)(tg * NT) * BD + (size_t)B0 * DIM;
        const unsigned long long* srow =
            (const unsigned long long*)(xT + (size_t)sr * DIM);
        unsigned short* dh = &hHi[sr * HSTR];
        unsigned short* dl = &hLo[sr * HSTR];
        #pragma unroll
        for (int i = 0; i < 16; ++i) {
            unsigned hp, lp;
            split_pair(srow[su + 32 * i], hp, lp);
            *(unsigned*)(dh + 2 * (su + 32 * i)) = hp;
            *(unsigned*)(dl + 2 * (su + 32 * i)) = lp;
        }
    }

    for (int tt = 0; tt < NT; ++tt) {
        const int t = tg * NT + tt;
        float* outT = out + (size_t)t * BD;

        unsigned long long xr[16];
        if (tt + 1 < NT) {
            const float* xN = x + (size_t)(t + 1) * BD + (size_t)B0 * DIM;
            const unsigned long long* srow =
                (const unsigned long long*)(xN + (size_t)sr * DIM);
            #pragma unroll
            for (int i = 0; i < 16; ++i) xr[i] = srow[su + 32 * i];
        }

        __syncthreads();   // B1: LDS tile tt ready; redS consumed

        f32x4 acc = {0.f, 0.f, 0.f, 0.f};
        {
            const unsigned short* rh = &hHi[(l & 15) * HSTR + K0];
            const unsigned short* rl = &hLo[(l & 15) * HSTR + K0];
            #pragma unroll
            for (int s = 0; s < 16; ++s) {
                const bf16x8 ah = *(const bf16x8*)(rh + 32 * s + 8 * q);
                const bf16x8 al = *(const bf16x8*)(rl + 32 * s + 8 * q);
                acc = __builtin_amdgcn_mfma_f32_16x16x32_bf16(ah, Bhi[s], acc, 0, 0, 0);
                acc = __builtin_amdgcn_mfma_f32_16x16x32_bf16(al, Bhi[s], acc, 0, 0, 0);
                acc = __builtin_amdgcn_mfma_f32_16x16x32_bf16(ah, Blo[s], acc, 0, 0, 0);
            }
        }

        if (w & 1) redS[(w >> 1) * 64 + l] = acc;
        __syncthreads();   // B2: all LDS reads of tile tt done

        if (!(w & 1)) {
            const f32x4 p = redS[(w >> 1) * 64 + l];
            #pragma unroll
            for (int i = 0; i < 4; ++i)
                outT[(size_t)(B0 + q * 4 + i) * DIM + cb + n] = acc[i] + p[i] + bv;
        }

        if (tt + 1 < NT) {
            unsigned short* dh = &hHi[sr * HSTR];
            unsigned short* dl = &hLo[sr * HSTR];
            #pragma unroll
            for (int i = 0; i < 16; ++i) {
                unsigned hp, lp;
                split_pair(xr[i], hp, lp);
                *(unsigned*)(dh + 2 * (su + 32 * i)) = hp;
                *(unsigned*)(dl + 2 * (su + 32 * i)) = lp;
            }
        }
    }
}

// ---------------------------------------------------------------------------
// Phase 2: persistent MFMA scan, per-wave tagged mailboxes.
// Block: bt = bid&7 (XCD-affine group), ct = bid>>3.
// Tag slot = bt*64 + global col-tile (0..63); value = t+1 when h_t is out.
// ---------------------------------------------------------------------------
__global__ __launch_bounds__(512) void rnn_scan(
    const float* __restrict__ h0,
    const float* __restrict__ Wh,
    float* out,
    unsigned* tags,
    unsigned short* hX)
{
    __shared__ unsigned short hS[16 * HSTR];
    __shared__ f32x4 redS[256];

    const int tid = threadIdx.x;
    const int p   = blockIdx.x;
    const int bt  = p & 7;           // XCD-affine: group bt lives on one XCD
    const int ct  = p >> 3;
    const int B0  = bt * 16;
    const int Cb  = ct * 64;

    const int w = tid >> 6;
    const int l = tid & 63;
    const int n = l & 15;
    const int q = l >> 4;
    const int cb = Cb + (w >> 1) * 16;
    const int K0 = (w & 1) * 512;

    bf16x8 Bhi[16], Blo[16];
    #pragma unroll
    for (int s = 0; s < 16; ++s) {
        bf16x8 hi, lo;
        #pragma unroll
        for (int j = 0; j < 8; ++j) {
            const int k = K0 + 32 * s + q * 8 + j;
            const float wv = Wh[(size_t)k * DIM + cb + n];
            const unsigned short h16 = f2bf_rne(wv);
            hi[j] = (short)h16;
            lo[j] = (short)f2bf_rne(wv - bf2f(h16));
        }
        Bhi[s] = hi;
        Blo[s] = lo;
    }

    const int sr = tid >> 5;           // t==0 staging: row (32 threads/row)
    const int su = tid & 31;           // t==0 staging: ulong lane in row
    const int qq = tid & 3;            // t>0 staging: row quad
    const int c0 = (tid >> 2) & 127;   // t>0 staging: col-group base

    // my wave's tag slot (producers) and my 2 watched slots (consumers)
    const int myslot = bt * 64 + ct * 4 + (w >> 1);
    const unsigned* tg0 = &tags[(bt * 64 + (c0 >> 2)) * FLAGSTR];
    const unsigned* tg1 = &tags[(bt * 64 + 32 + (c0 >> 2)) * FLAGSTR];

    for (int t = 0; t < SEQ; ++t) {
        float* outT = out + (size_t)t * BD;

        // xp prefetch (xp_pers completed before this kernel launched)
        float xpv[4];
        if (!(w & 1)) {
            #pragma unroll
            for (int i = 0; i < 4; ++i)
                xpv[i] = __builtin_nontemporal_load(
                    &outT[(size_t)(B0 + q * 4 + i) * DIM + cb + n]);
        }

        if (t == 0) {
            const float* hsrc = h0 + (size_t)B0 * DIM;
            const unsigned long long* srow =
                (const unsigned long long*)(hsrc + (size_t)sr * DIM);
            unsigned short* drow = &hS[sr * HSTR];
            #pragma unroll
            for (int i = 0; i < 16; ++i) {
                const unsigned long long v = srow[su + 32 * i];
                const float f0 = __builtin_bit_cast(float, (unsigned)(v & 0xFFFFFFFFull));
                const float f1 = __builtin_bit_cast(float, (unsigned)(v >> 32));
                const unsigned pk =
                    (unsigned)f2bf_rne(f0) | ((unsigned)f2bf_rne(f1) << 16);
                *(unsigned*)(drow + 2 * (su + 32 * i)) = pk;
            }
        } else {
            // wait for the 2 tags covering my 8 units (posted per-wave by
            // producers at the earliest wave-local instant)
            const unsigned need = (unsigned)t;
            while (__hip_atomic_load(tg0, __ATOMIC_RELAXED,
                                     __HIP_MEMORY_SCOPE_AGENT) < need)
                __builtin_amdgcn_s_sleep(1);
            while (__hip_atomic_load(tg1, __ATOMIC_RELAXED,
                                     __HIP_MEMORY_SCOPE_AGENT) < need)
                __builtin_amdgcn_s_sleep(1);
            asm volatile("" ::: "memory");   // pin data loads after the spin

            // bf16 side-channel: 8 x 8B bypass loads + in-register transpose
            const unsigned short* gX = hX + (size_t)((t - 1) & 1) * (8 * HXGRP)
                                          + (size_t)bt * HXGRP;
            #pragma unroll
            for (int half = 0; half < 2; ++half) {
                const int cp = c0 + half * 128;
                unsigned long long L[4];
                #pragma unroll
                for (int cc = 0; cc < 4; ++cc)
                    L[cc] = __hip_atomic_load(
                        (const unsigned long long*)(gX + (size_t)(4 * cp + cc) * 16 + qq * 4),
                        __ATOMIC_RELAXED, __HIP_MEMORY_SCOPE_AGENT);
                #pragma unroll
                for (int i = 0; i < 2; ++i) {
                    const unsigned a0 = (unsigned)(L[0] >> (32 * i));
                    const unsigned a1 = (unsigned)(L[1] >> (32 * i));
                    const unsigned a2 = (unsigned)(L[2] >> (32 * i));
                    const unsigned a3 = (unsigned)(L[3] >> (32 * i));
                    const unsigned r0w0 = (a0 & 0xFFFFu) | (a1 << 16);
                    const unsigned r0w1 = (a2 & 0xFFFFu) | (a3 << 16);
                    const unsigned r1w0 = (a0 >> 16) | (a1 & 0xFFFF0000u);
                    const unsigned r1w1 = (a2 >> 16) | (a3 & 0xFFFF0000u);
                    *(unsigned long long*)&hS[(4 * qq + 2 * i) * HSTR + 4 * cp] =
                        (unsigned long long)r0w0 | ((unsigned long long)r0w1 << 32);
                    *(unsigned long long*)&hS[(4 * qq + 2 * i + 1) * HSTR + 4 * cp] =
                        (unsigned long long)r1w0 | ((unsigned long long)r1w1 << 32);
                }
            }
        }

        __syncthreads();   // B1: hS(t) staged by all threads

        f32x4 acc = {0.f, 0.f, 0.f, 0.f};
        {
            const unsigned short* hrow = &hS[(l & 15) * HSTR + K0];
            #pragma unroll
            for (int s = 0; s < 16; ++s) {
                const bf16x8 a = *(const bf16x8*)(hrow + 32 * s + 8 * q);
                acc = __builtin_amdgcn_mfma_f32_16x16x32_bf16(a, Bhi[s], acc, 0, 0, 0);
                acc = __builtin_amdgcn_mfma_f32_16x16x32_bf16(a, Blo[s], acc, 0, 0, 0);
            }
        }

        if (w & 1) redS[(w >> 1) * 64 + l] = acc;
        __syncthreads();   // B2: all hS(t) reads done; redS ready

        if (!(w & 1)) {
            const f32x4 pp = redS[(w >> 1) * 64 + l];
            const float v0 = tanhf(acc[0] + pp[0] + xpv[0]);
            const float v1 = tanhf(acc[1] + pp[1] + xpv[1]);
            const float v2 = tanhf(acc[2] + pp[2] + xpv[2]);
            const float v3 = tanhf(acc[3] + pp[3] + xpv[3]);

            if (t < SEQ - 1) {
                // bf16 side-channel store, wave-local drain, per-wave tag post
                const unsigned p0 = (unsigned)f2bf_rne(v0) | ((unsigned)f2bf_rne(v1) << 16);
                const unsigned p1 = (unsigned)f2bf_rne(v2) | ((unsigned)f2bf_rne(v3) << 16);
                unsigned short* gW = hX + (size_t)(t & 1) * (8 * HXGRP)
                                        + (size_t)bt * HXGRP;
                __hip_atomic_store(
                    (unsigned long long*)(gW + (size_t)(cb + n) * 16 + q * 4),
                    (unsigned long long)p0 | ((unsigned long long)p1 << 32),
                    __ATOMIC_RELAXED, __HIP_MEMORY_SCOPE_AGENT);
                // drain THIS WAVE's stores to the coherence point (wave-scoped)
                asm volatile("s_waitcnt vmcnt(0)" ::: "memory");
                if (l == 0)
                    __hip_atomic_store(&tags[myslot * FLAGSTR], (unsigned)(t + 1),
                                       __ATOMIC_RELAXED, __HIP_MEMORY_SCOPE_AGENT);
            }

            // fp32 output stores: off the exchange critical path
            __builtin_nontemporal_store(v0, &outT[(size_t)(B0 + q * 4 + 0) * DIM + cb + n]);
            __builtin_nontemporal_store(v1, &outT[(size_t)(B0 + q * 4 + 1) * DIM + cb + n]);
            __builtin_nontemporal_store(v2, &outT[(size_t)(B0 + q * 4 + 2) * DIM + cb + n]);
            __builtin_nontemporal_store(v3, &outT[(size_t)(B0 + q * 4 + 3) * DIM + cb + n]);
        }
        // no tail barrier: B1 of the next step orders staging vs this step's
        // LDS reads (drained at B2); parity-slab safety comes from the tags.
    }
}

// ---------------------------------------------------------------------------
extern "C" void kernel_launch(void* const* d_in, const int* in_sizes, int n_in,
                              void* d_out, int out_size, void* d_ws, size_t ws_size,
                              hipStream_t stream) {
    const float* x  = (const float*)d_in[0];   // [S,B,D]
    const float* h0 = (const float*)d_in[1];   // [B,D]
    const float* Wx = (const float*)d_in[2];   // [D,D]
    const float* Wh = (const float*)d_in[3];   // [D,D]
    const float* b  = (const float*)d_in[4];   // [D]
    float* out = (float*)d_out;                // [S,B,D]
    unsigned* tags = (unsigned*)d_ws;                             // 32 KB
    unsigned short* hX = (unsigned short*)((char*)d_ws + 32768);  // 512 KB

    hipMemsetAsync(d_ws, 0, 512 * FLAGSTR * sizeof(unsigned), stream);

    xp_pers<<<dim3(XNB), dim3(512), 0, stream>>>(x, Wx, b, out);

    rnn_scan<<<dim3(NBLK), dim3(512), 0, stream>>>(h0, Wh, out, tags, hX);
}